// Round 2
// baseline (654.854 us; speedup 1.0000x reference)
//
#include <hip/hip_runtime.h>
#include <math.h>

typedef _Float16 f16;
typedef _Float16 f16x8 __attribute__((ext_vector_type(8)));
typedef _Float16 f16x4 __attribute__((ext_vector_type(4)));
typedef float f32x4 __attribute__((ext_vector_type(4)));

#define NM 16384   // nodes (K of big GEMM)
#define NE 4096    // hyperedges
#define ND 300     // feature dim
#define DP 320     // padded feature dim
#define JT 640     // 2*DP columns of Z

__device__ __forceinline__ int swz(int r) { return (r ^ (r >> 2)) & 3; }

#define GLOAD_LDS16(gsrc, ldst)                                              \
  __builtin_amdgcn_global_load_lds(                                          \
      (__attribute__((address_space(1))) void*)(gsrc),                       \
      (__attribute__((address_space(3))) void*)(ldst), 16, 0, 0)

// ---------------------------------------------------------------- k0: W_att^T -> fp16 (DPxDP)
__global__ void k0_wt(const float* __restrict__ Watt, f16* __restrict__ WT) {
  int idx = blockIdx.x * 256 + threadIdx.x;
  if (idx >= DP * DP) return;
  int j = idx / DP, d = idx % DP;
  float v = (j < ND && d < ND) ? Watt[d * ND + j] : 0.f;
  WT[(size_t)j * DP + d] = (f16)v;
}

// ---------------------------------------------------------------- k1a: X -> X16 [m][DP] and YT rows 320..639 (X^T)
__global__ __launch_bounds__(256) void k1a_xprep(const float* __restrict__ X,
                                                 f16* __restrict__ X16,
                                                 f16* __restrict__ YT) {
  __shared__ f16 tile[64][324];
  int m0 = blockIdx.x * 64;
  for (int idx = threadIdx.x; idx < 64 * 80; idx += 256) {
    int m = idx / 80, q = idx % 80;
    int d = q * 4;
    float4 v = make_float4(0.f, 0.f, 0.f, 0.f);
    if (d < ND) v = *(const float4*)(X + (size_t)(m0 + m) * ND + d);
    f16x4 hv;
    hv[0] = (f16)v.x; hv[1] = (f16)v.y; hv[2] = (f16)v.z; hv[3] = (f16)v.w;
    tile[m][d] = hv[0]; tile[m][d + 1] = hv[1];
    tile[m][d + 2] = hv[2]; tile[m][d + 3] = hv[3];
    *(f16x4*)(X16 + (size_t)(m0 + m) * DP + d) = hv;
  }
  __syncthreads();
  for (int idx = threadIdx.x; idx < DP * 8; idx += 256) {
    int d = idx >> 3, part = idx & 7;
    f16x8 hv;
#pragma unroll
    for (int i = 0; i < 8; ++i) hv[i] = tile[part * 8 + i][d];
    *(f16x8*)(YT + (size_t)(DP + d) * NM + m0 + part * 8) = hv;
  }
}

// ---------------------------------------------------------------- k1b: YT rows 0..319 = W^T @ X^T (fp16 MFMA)
__global__ __launch_bounds__(512, 2) void k1b_xat(const f16* __restrict__ WT,
                                                  const f16* __restrict__ X16,
                                                  f16* __restrict__ YT) {
  __shared__ __align__(16) char lds[49152];
  // layout: A buffers at 0 / 20480 (320 j-rows x 64B each)
  //         B buffers at 40960 / 45056 (64 m-rows x 64B each)
  const int t = threadIdx.x, lane = t & 63, wid = t >> 6;
  const int m0 = blockIdx.x * 64;
  const int row = lane & 15, g = lane >> 4;
  const int wj = wid & 3, wm = wid >> 2;
  int aoff[5], boff[2];
#pragma unroll
  for (int f = 0; f < 5; ++f) {
    int jr = wj * 80 + f * 16 + row;
    aoff[f] = jr * 64 + ((g ^ swz(jr)) << 4);
  }
#pragma unroll
  for (int fm = 0; fm < 2; ++fm) {
    int mr = wm * 32 + fm * 16 + row;
    boff[fm] = mr * 64 + ((g ^ swz(mr)) << 4);
  }
  f32x4 acc[5][2];
#pragma unroll
  for (int f = 0; f < 5; ++f)
#pragma unroll
    for (int fm = 0; fm < 2; ++fm)
#pragma unroll
      for (int r = 0; r < 4; ++r) acc[f][fm][r] = 0.f;

  auto stage = [&](int buf, int ks) {
    int k0 = ks * 32;
    char* A = lds + buf * 20480;
    char* B = lds + 40960 + buf * 4096;
    for (int c = wid; c < 24; c += 8) {
      if (c < 20) {
        int j = c * 16 + (lane >> 2), gg = lane & 3;
        GLOAD_LDS16(WT + (size_t)j * DP + k0 + 8 * (gg ^ swz(j)), A + c * 1024);
      } else {
        int cb = c - 20;
        int m = cb * 16 + (lane >> 2), gg = lane & 3;
        GLOAD_LDS16(X16 + (size_t)(m0 + m) * DP + k0 + 8 * (gg ^ swz(m)),
                    B + cb * 1024);
      }
    }
  };
  stage(0, 0);
  __syncthreads();
  for (int ks = 0; ks < 10; ++ks) {
    int cur = ks & 1;
    if (ks + 1 < 10) stage(cur ^ 1, ks + 1);
    const char* A = lds + cur * 20480;
    const char* B = lds + 40960 + cur * 4096;
    f16x8 b0 = *(const f16x8*)(B + boff[0]);
    f16x8 b1 = *(const f16x8*)(B + boff[1]);
#pragma unroll
    for (int f = 0; f < 5; ++f) {
      f16x8 a = *(const f16x8*)(A + aoff[f]);
      acc[f][0] = __builtin_amdgcn_mfma_f32_16x16x32_f16(a, b0, acc[f][0], 0, 0, 0);
      acc[f][1] = __builtin_amdgcn_mfma_f32_16x16x32_f16(a, b1, acc[f][1], 0, 0, 0);
    }
    __syncthreads();
  }
#pragma unroll
  for (int f = 0; f < 5; ++f)
#pragma unroll
    for (int fm = 0; fm < 2; ++fm)
#pragma unroll
      for (int r = 0; r < 4; ++r) {
        int j = wj * 80 + f * 16 + g * 4 + r;
        int m = m0 + wm * 32 + fm * 16 + row;
        YT[(size_t)j * NM + m] = (f16)acc[f][fm][r];
      }
}

// ---------------------------------------------------------------- k2: Z(4096x640) = inc^T @ Y  (the hot GEMM)
__global__ __launch_bounds__(512, 2) void k2_bigmm(const float* __restrict__ inc,
                                                   const f16* __restrict__ YT,
                                                   float* __restrict__ Z) {
  __shared__ __align__(16) char lds[45056];
  // layout: A buffers at 0 / 2048 (32 e-rows x 64B each)
  //         B buffers at 4096 / 24576 (320 j-rows x 64B each)
  const int t = threadIdx.x, lane = t & 63, wid = t >> 6;
  const int bx = blockIdx.x;
  const int eb = bx & 127, jb = bx >> 7;       // pair (eb, jb=0/1) lands on same XCD
  const int e0 = eb * 32;
  const int jg0 = jb * DP;
  const int ak = t >> 4, aep = t & 15;         // A-stage: row k (0..31), e-pair
  const int row = lane & 15, g = lane >> 4;
  const int we = wid >> 2, wj = wid & 3;
  const int ea = we * 16 + row;
  const int aoff = ea * 64 + ((g ^ swz(ea)) << 4);
  int boff[5];
#pragma unroll
  for (int f = 0; f < 5; ++f) {
    int jr = wj * 80 + f * 16 + row;
    boff[f] = jr * 64 + ((g ^ swz(jr)) << 4);
  }
  f32x4 acc[5];
#pragma unroll
  for (int f = 0; f < 5; ++f)
#pragma unroll
    for (int r = 0; r < 4; ++r) acc[f][r] = 0.f;

  auto loadA = [&](int ks) {
    return *(const float2*)(inc + (size_t)(ks * 32 + ak) * NE + e0 + aep * 2);
  };
  auto writeA = [&](int buf, float2 v) {
    char* A = lds + buf * 2048;
    int e = aep * 2;
    *(f16*)(A + e * 64 + ((((ak >> 3)) ^ swz(e)) << 4) + (ak & 7) * 2) = (f16)v.x;
    e = aep * 2 + 1;
    *(f16*)(A + e * 64 + ((((ak >> 3)) ^ swz(e)) << 4) + (ak & 7) * 2) = (f16)v.y;
  };
  auto stageB = [&](int buf, int ks) {
    int k0 = ks * 32;
    char* B = lds + 4096 + buf * 20480;
    for (int c = wid; c < 20; c += 8) {
      int j = c * 16 + (lane >> 2), gg = lane & 3;
      GLOAD_LDS16(YT + (size_t)(jg0 + j) * NM + k0 + 8 * (gg ^ swz(j)), B + c * 1024);
    }
  };

  {  // prologue
    float2 v = loadA(0);
    stageB(0, 0);
    writeA(0, v);
  }
  __syncthreads();
  for (int ks = 0; ks < 512; ++ks) {
    int cur = ks & 1;
    float2 v;
    bool has = (ks + 1 < 512);
    if (has) {            // issue next-tile loads early (latency hides under MFMA)
      v = loadA(ks + 1);
      stageB(cur ^ 1, ks + 1);
    }
    const char* A = lds + cur * 2048;
    const char* B = lds + 4096 + cur * 20480;
    f16x8 a = *(const f16x8*)(A + aoff);
#pragma unroll
    for (int f = 0; f < 5; ++f) {
      f16x8 b = *(const f16x8*)(B + boff[f]);
      acc[f] = __builtin_amdgcn_mfma_f32_16x16x32_f16(a, b, acc[f], 0, 0, 0);
    }
    if (has) writeA(cur ^ 1, v);   // convert+LDS-write late
    __syncthreads();
  }
#pragma unroll
  for (int f = 0; f < 5; ++f) {
    int jgl = jg0 + wj * 80 + f * 16 + row;
#pragma unroll
    for (int r = 0; r < 4; ++r) {
      int egl = e0 + we * 16 + g * 4 + r;
      Z[(size_t)egl * JT + jgl] = acc[f][r];
    }
  }
}

// ---------------------------------------------------------------- k3: per-edge softmax + projection + residual + scores
__global__ __launch_bounds__(256) void k3_edge(const float* __restrict__ Z,
                                               const float* __restrict__ edge_feats,
                                               const float* __restrict__ Wproj,
                                               const float* __restrict__ alphaP,
                                               const float* __restrict__ ecWatt,
                                               float* __restrict__ ef,
                                               float* __restrict__ scores) {
  __shared__ float efw[16][304];
  const int t = threadIdx.x, lane = t & 63, w = t >> 6;
  const int e0 = blockIdx.x * 16;
  // phase 1: feature softmax, weight ef0
  for (int el = 0; el < 4; ++el) {
    int e = e0 + w * 4 + el;
    const float* zr = Z + (size_t)e * JT;
    float p[5];
    float mx = -1e30f;
#pragma unroll
    for (int u = 0; u < 5; ++u) {
      int d = u * 64 + lane;
      p[u] = (d < ND) ? zr[d] : -1e30f;
      mx = fmaxf(mx, p[u]);
    }
    for (int o = 32; o; o >>= 1) mx = fmaxf(mx, __shfl_xor(mx, o));
    float s = 0.f;
#pragma unroll
    for (int u = 0; u < 5; ++u) {
      int d = u * 64 + lane;
      float pe = (d < ND) ? expf(p[u] - mx) : 0.f;
      p[u] = pe;
      s += pe;
    }
    for (int o = 32; o; o >>= 1) s += __shfl_xor(s, o);
    float inv = 1.f / s;
#pragma unroll
    for (int u = 0; u < 5; ++u) {
      int d = u * 64 + lane;
      if (d < 304) efw[w * 4 + el][d] = (d < ND) ? zr[DP + d] * p[u] * inv : 0.f;
    }
  }
  __syncthreads();
  // phase 2: (ef0*attn) @ W_proj  + residual + attention score
  const int el = t >> 4, jl = t & 15;
  const int e = e0 + el;
  const float alpha = alphaP[0];
  const float* efwr = efw[el];
  float acc[19];
#pragma unroll
  for (int jj = 0; jj < 19; ++jj) acc[jj] = 0.f;
  for (int d = 0; d < ND; ++d) {
    float ew = efwr[d];
    const float* wr = Wproj + d * ND + jl;
#pragma unroll
    for (int jj = 0; jj < 19; ++jj) {
      int j = jl + jj * 16;
      if (j < ND) acc[jj] += ew * wr[jj * 16];
    }
  }
  float sc = 0.f;
#pragma unroll
  for (int jj = 0; jj < 19; ++jj) {
    int j = jl + jj * 16;
    float v = 0.f;
    if (j < ND) {
      v = alpha * edge_feats[(size_t)e * ND + j] + (1.f - alpha) * acc[jj];
      sc += v * ecWatt[j];
    }
    ef[(size_t)e * 304 + j] = v;
  }
  for (int o = 8; o; o >>= 1) sc += __shfl_xor(sc, o, 16);
  if (jl == 0) scores[e] = sc;
}

// ---------------------------------------------------------------- k4a: softmax over 4096 edge scores
__global__ __launch_bounds__(1024) void k4a_softmax(const float* __restrict__ scores,
                                                    float* __restrict__ w) {
  __shared__ float red[16];
  __shared__ float red2[16];
  const int t = threadIdx.x, lane = t & 63, wv = t >> 6;
  float v[4];
  float mx = -1e30f;
#pragma unroll
  for (int u = 0; u < 4; ++u) {
    v[u] = scores[t + u * 1024];
    mx = fmaxf(mx, v[u]);
  }
  for (int o = 32; o; o >>= 1) mx = fmaxf(mx, __shfl_xor(mx, o));
  if (lane == 0) red[wv] = mx;
  __syncthreads();
  float m2 = red[0];
  for (int i = 1; i < 16; ++i) m2 = fmaxf(m2, red[i]);
  float s = 0.f;
#pragma unroll
  for (int u = 0; u < 4; ++u) {
    v[u] = expf(v[u] - m2);
    s += v[u];
  }
  for (int o = 32; o; o >>= 1) s += __shfl_xor(s, o);
  if (lane == 0) red2[wv] = s;
  __syncthreads();
  float S = 0.f;
  for (int i = 0; i < 16; ++i) S += red2[i];
  float inv = 1.f / S;
#pragma unroll
  for (int u = 0; u < 4; ++u) w[t + u * 1024] = v[u] * inv;
}

// ---------------------------------------------------------------- k4b: partial weighted pooling (64 edges/block)
__global__ __launch_bounds__(256) void k4b_pool(const float* __restrict__ ef,
                                                const float* __restrict__ w,
                                                float* __restrict__ partial) {
  const int b = blockIdx.x, t = threadIdx.x;
  const int e0 = b * 64;
  for (int j = t; j < 304; j += 256) {
    float acc = 0.f;
    for (int e = 0; e < 64; ++e) acc += w[e0 + e] * ef[(size_t)(e0 + e) * 304 + j];
    partial[b * 304 + j] = acc;
  }
}

// ---------------------------------------------------------------- k4c: final reduce + two matvecs -> 3 logits
__global__ __launch_bounds__(256) void k4c_final(const float* __restrict__ partial,
                                                 const float* __restrict__ ecWp,
                                                 const float* __restrict__ ecb,
                                                 const float* __restrict__ fcW,
                                                 const float* __restrict__ fcb,
                                                 float* __restrict__ out) {
  __shared__ float pooled[304];
  __shared__ float o[304];
  const int t = threadIdx.x;
  for (int j = t; j < 304; j += 256) {
    float acc = 0.f;
    for (int b = 0; b < 64; ++b) acc += partial[b * 304 + j];
    pooled[j] = acc;
  }
  __syncthreads();
  for (int j2 = t; j2 < ND; j2 += 256) {
    float acc = ecb[j2];
    for (int j = 0; j < ND; ++j) acc += pooled[j] * ecWp[j * ND + j2];
    o[j2] = acc;
  }
  __syncthreads();
  if (t < 3) {
    float acc = fcb[t];
    for (int j2 = 0; j2 < ND; ++j2) acc += o[j2] * fcW[j2 * 3 + t];
    out[t] = acc;
  }
}

// ----------------------------------------------------------------
extern "C" void kernel_launch(void* const* d_in, const int* in_sizes, int n_in,
                              void* d_out, int out_size, void* d_ws, size_t ws_size,
                              hipStream_t stream) {
  const float* X = (const float*)d_in[0];
  const float* EF = (const float*)d_in[1];
  const float* INC = (const float*)d_in[2];
  const float* WATT = (const float*)d_in[3];
  const float* WPROJ = (const float*)d_in[4];
  const float* ALPHA = (const float*)d_in[5];
  const float* ECATT = (const float*)d_in[6];
  const float* ECWP = (const float*)d_in[7];
  const float* ECB = (const float*)d_in[8];
  const float* FCW = (const float*)d_in[9];
  const float* FCB = (const float*)d_in[10];

  char* ws = (char*)d_ws;
  f16* YT = (f16*)(ws);                      // 640*16384*2  = 20971520
  f16* X16 = (f16*)(ws + 20971520);          // 16384*320*2  = 10485760
  f16* WT = (f16*)(ws + 31457280);           // 320*320*2    =   204800
  float* Z = (float*)(ws + 31662080);        // 4096*640*4   = 10485760
  float* ef = (float*)(ws + 42147840);       // 4096*304*4   =  4980736
  float* sc = (float*)(ws + 47128576);       // 4096*4
  float* wv = (float*)(ws + 47144960);       // 4096*4
  float* pp = (float*)(ws + 47161344);       // 64*304*4

  hipLaunchKernelGGL(k0_wt, dim3(400), dim3(256), 0, stream, WATT, WT);
  hipLaunchKernelGGL(k1a_xprep, dim3(256), dim3(256), 0, stream, X, X16, YT);
  hipLaunchKernelGGL(k1b_xat, dim3(256), dim3(512), 0, stream, WT, X16, YT);
  hipLaunchKernelGGL(k2_bigmm, dim3(256), dim3(512), 0, stream, INC, YT, Z);
  hipLaunchKernelGGL(k3_edge, dim3(256), dim3(256), 0, stream, Z, EF, WPROJ, ALPHA,
                     ECATT, ef, sc);
  hipLaunchKernelGGL(k4a_softmax, dim3(1), dim3(1024), 0, stream, sc, wv);
  hipLaunchKernelGGL(k4b_pool, dim3(64), dim3(256), 0, stream, ef, wv, pp);
  hipLaunchKernelGGL(k4c_final, dim3(1), dim3(256), 0, stream, pp, ECWP, ECB, FCW,
                     FCB, (float*)d_out);
}

// Round 3
// 420.953 us; speedup vs baseline: 1.5556x; 1.5556x over previous
//
#include <hip/hip_runtime.h>
#include <math.h>

typedef _Float16 f16;
typedef _Float16 f16x8 __attribute__((ext_vector_type(8)));
typedef _Float16 f16x4 __attribute__((ext_vector_type(4)));
typedef float f32x4 __attribute__((ext_vector_type(4)));

#define NM 16384   // nodes (K of big GEMM)
#define NE 4096    // hyperedges
#define ND 300     // feature dim
#define DP 320     // padded feature dim
#define JT 640     // 2*DP columns of Z

__device__ __forceinline__ int swz(int r) { return (r ^ (r >> 2)) & 3; }

#define GLOAD_LDS16(gsrc, ldst)                                              \
  __builtin_amdgcn_global_load_lds(                                          \
      (__attribute__((address_space(1))) void*)(gsrc),                       \
      (__attribute__((address_space(3))) void*)(ldst), 16, 0, 0)

// ---------------------------------------------------------------- k0: W_att^T -> fp16 (DPxDP)
__global__ void k0_wt(const float* __restrict__ Watt, f16* __restrict__ WT) {
  int idx = blockIdx.x * 256 + threadIdx.x;
  if (idx >= DP * DP) return;
  int j = idx / DP, d = idx % DP;
  float v = (j < ND && d < ND) ? Watt[d * ND + j] : 0.f;
  WT[(size_t)j * DP + d] = (f16)v;
}

// ---------------------------------------------------------------- k1a: X -> X16 [m][DP] and YT rows 320..639 (X^T)
__global__ __launch_bounds__(256) void k1a_xprep(const float* __restrict__ X,
                                                 f16* __restrict__ X16,
                                                 f16* __restrict__ YT) {
  __shared__ f16 tile[64][324];
  int m0 = blockIdx.x * 64;
  for (int idx = threadIdx.x; idx < 64 * 80; idx += 256) {
    int m = idx / 80, q = idx % 80;
    int d = q * 4;
    float4 v = make_float4(0.f, 0.f, 0.f, 0.f);
    if (d < ND) v = *(const float4*)(X + (size_t)(m0 + m) * ND + d);
    f16x4 hv;
    hv[0] = (f16)v.x; hv[1] = (f16)v.y; hv[2] = (f16)v.z; hv[3] = (f16)v.w;
    tile[m][d] = hv[0]; tile[m][d + 1] = hv[1];
    tile[m][d + 2] = hv[2]; tile[m][d + 3] = hv[3];
    *(f16x4*)(X16 + (size_t)(m0 + m) * DP + d) = hv;
  }
  __syncthreads();
  for (int idx = threadIdx.x; idx < DP * 8; idx += 256) {
    int d = idx >> 3, part = idx & 7;
    f16x8 hv;
#pragma unroll
    for (int i = 0; i < 8; ++i) hv[i] = tile[part * 8 + i][d];
    *(f16x8*)(YT + (size_t)(DP + d) * NM + m0 + part * 8) = hv;
  }
}

// ---------------------------------------------------------------- k1b: YT rows 0..319 = W^T @ X^T (fp16 MFMA)
__global__ __launch_bounds__(512, 2) void k1b_xat(const f16* __restrict__ WT,
                                                  const f16* __restrict__ X16,
                                                  f16* __restrict__ YT) {
  __shared__ __align__(16) char lds[49152];
  const int t = threadIdx.x, lane = t & 63, wid = t >> 6;
  const int m0 = blockIdx.x * 64;
  const int row = lane & 15, g = lane >> 4;
  const int wj = wid & 3, wm = wid >> 2;
  int aoff[5], boff[2];
#pragma unroll
  for (int f = 0; f < 5; ++f) {
    int jr = wj * 80 + f * 16 + row;
    aoff[f] = jr * 64 + ((g ^ swz(jr)) << 4);
  }
#pragma unroll
  for (int fm = 0; fm < 2; ++fm) {
    int mr = wm * 32 + fm * 16 + row;
    boff[fm] = mr * 64 + ((g ^ swz(mr)) << 4);
  }
  f32x4 acc[5][2];
#pragma unroll
  for (int f = 0; f < 5; ++f)
#pragma unroll
    for (int fm = 0; fm < 2; ++fm)
#pragma unroll
      for (int r = 0; r < 4; ++r) acc[f][fm][r] = 0.f;

  auto stage = [&](int buf, int ks) {
    int k0 = ks * 32;
    char* A = lds + buf * 20480;
    char* B = lds + 40960 + buf * 4096;
    for (int c = wid; c < 24; c += 8) {
      if (c < 20) {
        int j = c * 16 + (lane >> 2), gg = lane & 3;
        GLOAD_LDS16(WT + (size_t)j * DP + k0 + 8 * (gg ^ swz(j)), A + c * 1024);
      } else {
        int cb = c - 20;
        int m = cb * 16 + (lane >> 2), gg = lane & 3;
        GLOAD_LDS16(X16 + (size_t)(m0 + m) * DP + k0 + 8 * (gg ^ swz(m)),
                    B + cb * 1024);
      }
    }
  };
  stage(0, 0);
  __syncthreads();
  for (int ks = 0; ks < 10; ++ks) {
    int cur = ks & 1;
    if (ks + 1 < 10) stage(cur ^ 1, ks + 1);
    const char* A = lds + cur * 20480;
    const char* B = lds + 40960 + cur * 4096;
    f16x8 b0 = *(const f16x8*)(B + boff[0]);
    f16x8 b1 = *(const f16x8*)(B + boff[1]);
#pragma unroll
    for (int f = 0; f < 5; ++f) {
      f16x8 a = *(const f16x8*)(A + aoff[f]);
      acc[f][0] = __builtin_amdgcn_mfma_f32_16x16x32_f16(a, b0, acc[f][0], 0, 0, 0);
      acc[f][1] = __builtin_amdgcn_mfma_f32_16x16x32_f16(a, b1, acc[f][1], 0, 0, 0);
    }
    __syncthreads();
  }
#pragma unroll
  for (int f = 0; f < 5; ++f)
#pragma unroll
    for (int fm = 0; fm < 2; ++fm)
#pragma unroll
      for (int r = 0; r < 4; ++r) {
        int j = wj * 80 + f * 16 + g * 4 + r;
        int m = m0 + wm * 32 + fm * 16 + row;
        YT[(size_t)j * NM + m] = (f16)acc[f][fm][r];
      }
}

// ---------------------------------------------------------------- k2: Z(4096x640) = inc^T @ Y  (the hot GEMM, v2)
// BM=64(e) x BN=160(j) x BK=64, grid 256 = 64 eb x 4 jn, 8 waves (4e x 2j),
// wave tile 16e x 80j. 4-deep LDS ring, 1 raw barrier/step, counted vmcnt.
#define K2WAIT(N) asm volatile("s_waitcnt vmcnt(" #N ") lgkmcnt(0)" ::: "memory")
#define K2BAR()                                        \
  do {                                                 \
    asm volatile("" ::: "memory");                     \
    __builtin_amdgcn_s_barrier();                      \
    asm volatile("" ::: "memory");                     \
    __builtin_amdgcn_sched_barrier(0);                 \
  } while (0)

__global__ __launch_bounds__(512, 1) void k2_bigmm(const float* __restrict__ inc,
                                                   const f16* __restrict__ YT,
                                                   float* __restrict__ Z) {
  // bufB[s] at s*20480 (160 rows x 128B), s=0..3 -> 81920 B
  // bufA[s] at 81920 + s*8192 (64 rows x 128B)   -> 114688 B total
  __shared__ __align__(16) char lds[114688];
  const int t = threadIdx.x, lane = t & 63, wid = t >> 6;
  const int bx = blockIdx.x;
  const int eb = bx & 63, jn = bx >> 6;   // jn-blocks of one eb land on same XCD
  const int e0 = eb * 64;
  const int j0 = jn * 160;
  // compute mapping: 8 waves = 4(e) x 2(j); wave tile 16e x 80j
  const int we = wid >> 1, wjj = wid & 1;
  const int row = lane & 15, g = lane >> 4;
  int aoff[2], boff[2][5];
#pragma unroll
  for (int kk = 0; kk < 2; ++kk) {
    int erow = we * 16 + row;
    aoff[kk] = erow * 128 + (((kk * 4 + g) ^ (erow & 7)) & 7) * 16;
#pragma unroll
    for (int f = 0; f < 5; ++f) {
      int jl = wjj * 80 + f * 16 + row;
      boff[kk][f] = jl * 128 + (((kk * 4 + g) ^ (jl & 7)) & 7) * 16;
    }
  }
  // A-staging mapping: e_l (6b), qb (3b) -> thread covers 4 k-pairs
  const int e_l = (lane & 15) + 16 * (wid & 3);
  const int qb = (lane >> 4) + 4 * (wid >> 2);

  f32x4 acc[5];
#pragma unroll
  for (int f = 0; f < 5; ++f)
#pragma unroll
    for (int r = 0; r < 4; ++r) acc[f][r] = 0.f;

  float rA0[8], rA1[8];

#define STAGE_AB(T2, FILL)                                                     \
  {                                                                            \
    const int k0_ = (T2) * 64;                                                 \
    char* dB_ = lds + ((T2) & 3) * 20480;                                      \
    for (int c = wid; c < 20; c += 8) {                                        \
      int rr_ = 8 * c + (lane >> 3);                                           \
      GLOAD_LDS16(                                                             \
          YT + (size_t)(j0 + rr_) * NM + k0_ + 8 * ((lane & 7) ^ (rr_ & 7)),   \
          dB_ + c * 1024);                                                     \
    }                                                                          \
    const float* pA_ = inc + (size_t)k0_ * NE + e0 + e_l;                      \
    _Pragma("unroll")                                                          \
    for (int z = 0; z < 4; ++z) {                                              \
      FILL[2 * z] = pA_[(size_t)(2 * qb + 16 * z) * NE];                       \
      FILL[2 * z + 1] = pA_[(size_t)(2 * qb + 16 * z + 1) * NE];               \
    }                                                                          \
  }

#define WRITE_A(USE, BSW)                                                      \
  {                                                                            \
    char* dA_ = lds + 81920 + (BSW) * 8192;                                    \
    _Pragma("unroll")                                                          \
    for (int z = 0; z < 4; ++z) {                                              \
      int q_ = qb + 8 * z;                                                     \
      union { f16 h[2]; uint32_t u; } cv_;                                     \
      cv_.h[0] = (f16)USE[2 * z];                                              \
      cv_.h[1] = (f16)USE[2 * z + 1];                                          \
      *(uint32_t*)(dA_ + e_l * 128 + (((q_ >> 2) ^ (e_l & 7)) & 7) * 16 +      \
                   (q_ & 3) * 4) = cv_.u;                                      \
    }                                                                          \
  }

#define K2COMPUTE(BS)                                                          \
  {                                                                            \
    const char* A_ = lds + 81920 + (BS) * 8192;                                \
    const char* B_ = lds + (BS) * 20480;                                       \
    __builtin_amdgcn_s_setprio(1);                                             \
    _Pragma("unroll")                                                          \
    for (int kk = 0; kk < 2; ++kk) {                                           \
      f16x8 a_ = *(const f16x8*)(A_ + aoff[kk]);                               \
      _Pragma("unroll")                                                        \
      for (int f = 0; f < 5; ++f) {                                            \
        f16x8 b_ = *(const f16x8*)(B_ + boff[kk][f]);                          \
        acc[f] = __builtin_amdgcn_mfma_f32_16x16x32_f16(a_, b_, acc[f], 0, 0, 0); \
      }                                                                        \
    }                                                                          \
    __builtin_amdgcn_s_setprio(0);                                             \
  }

  // prologue: stage tiles 0 and 1 (A in regs, B in LDS)
  STAGE_AB(0, rA0);
  STAGE_AB(1, rA1);

  // main loop: T = 256 K-steps; iters 0..251 fully pipelined
  for (int tt = 0; tt < 252; tt += 2) {
    WRITE_A(rA0, tt & 3);
    STAGE_AB(tt + 2, rA0);
    if (wid < 4) { K2WAIT(22); } else { K2WAIT(20); }
    K2BAR();
    K2COMPUTE(tt & 3);

    WRITE_A(rA1, (tt + 1) & 3);
    STAGE_AB(tt + 3, rA1);
    if (wid < 4) { K2WAIT(22); } else { K2WAIT(20); }
    K2BAR();
    K2COMPUTE((tt + 1) & 3);
  }
  // t=252, t=253: still stage 254/255
  WRITE_A(rA0, 0);
  STAGE_AB(254, rA0);
  if (wid < 4) { K2WAIT(22); } else { K2WAIT(20); }
  K2BAR();
  K2COMPUTE(0);

  WRITE_A(rA1, 1);
  STAGE_AB(255, rA1);
  if (wid < 4) { K2WAIT(22); } else { K2WAIT(20); }
  K2BAR();
  K2COMPUTE(1);

  // t=254: no staging; leave tile 255's batch in flight
  WRITE_A(rA0, 2);
  if (wid < 4) { K2WAIT(11); } else { K2WAIT(10); }
  K2BAR();
  K2COMPUTE(2);

  // t=255: drain all
  WRITE_A(rA1, 3);
  K2WAIT(0);
  K2BAR();
  K2COMPUTE(3);

  // epilogue: store C
#pragma unroll
  for (int f = 0; f < 5; ++f) {
    int jgl = j0 + wjj * 80 + f * 16 + row;
#pragma unroll
    for (int r = 0; r < 4; ++r) {
      int egl = e0 + we * 16 + g * 4 + r;
      Z[(size_t)egl * JT + jgl] = acc[f][r];
    }
  }
#undef STAGE_AB
#undef WRITE_A
#undef K2COMPUTE
}

// ---------------------------------------------------------------- k3: per-edge softmax + projection + residual + scores
__global__ __launch_bounds__(256) void k3_edge(const float* __restrict__ Z,
                                               const float* __restrict__ edge_feats,
                                               const float* __restrict__ Wproj,
                                               const float* __restrict__ alphaP,
                                               const float* __restrict__ ecWatt,
                                               float* __restrict__ ef,
                                               float* __restrict__ scores) {
  __shared__ float efw[16][304];
  const int t = threadIdx.x, lane = t & 63, w = t >> 6;
  const int e0 = blockIdx.x * 16;
  for (int el = 0; el < 4; ++el) {
    int e = e0 + w * 4 + el;
    const float* zr = Z + (size_t)e * JT;
    float p[5];
    float mx = -1e30f;
#pragma unroll
    for (int u = 0; u < 5; ++u) {
      int d = u * 64 + lane;
      p[u] = (d < ND) ? zr[d] : -1e30f;
      mx = fmaxf(mx, p[u]);
    }
    for (int o = 32; o; o >>= 1) mx = fmaxf(mx, __shfl_xor(mx, o));
    float s = 0.f;
#pragma unroll
    for (int u = 0; u < 5; ++u) {
      int d = u * 64 + lane;
      float pe = (d < ND) ? expf(p[u] - mx) : 0.f;
      p[u] = pe;
      s += pe;
    }
    for (int o = 32; o; o >>= 1) s += __shfl_xor(s, o);
    float inv = 1.f / s;
#pragma unroll
    for (int u = 0; u < 5; ++u) {
      int d = u * 64 + lane;
      if (d < 304) efw[w * 4 + el][d] = (d < ND) ? zr[DP + d] * p[u] * inv : 0.f;
    }
  }
  __syncthreads();
  const int el = t >> 4, jl = t & 15;
  const int e = e0 + el;
  const float alpha = alphaP[0];
  const float* efwr = efw[el];
  float acc[19];
#pragma unroll
  for (int jj = 0; jj < 19; ++jj) acc[jj] = 0.f;
  for (int d = 0; d < ND; ++d) {
    float ew = efwr[d];
    const float* wr = Wproj + d * ND + jl;
#pragma unroll
    for (int jj = 0; jj < 19; ++jj) {
      int j = jl + jj * 16;
      if (j < ND) acc[jj] += ew * wr[jj * 16];
    }
  }
  float sc = 0.f;
#pragma unroll
  for (int jj = 0; jj < 19; ++jj) {
    int j = jl + jj * 16;
    float v = 0.f;
    if (j < ND) {
      v = alpha * edge_feats[(size_t)e * ND + j] + (1.f - alpha) * acc[jj];
      sc += v * ecWatt[j];
    }
    ef[(size_t)e * 304 + j] = v;
  }
  for (int o = 8; o; o >>= 1) sc += __shfl_xor(sc, o, 16);
  if (jl == 0) scores[e] = sc;
}

// ---------------------------------------------------------------- k4a: softmax over 4096 edge scores
__global__ __launch_bounds__(1024) void k4a_softmax(const float* __restrict__ scores,
                                                    float* __restrict__ w) {
  __shared__ float red[16];
  __shared__ float red2[16];
  const int t = threadIdx.x, lane = t & 63, wv = t >> 6;
  float v[4];
  float mx = -1e30f;
#pragma unroll
  for (int u = 0; u < 4; ++u) {
    v[u] = scores[t + u * 1024];
    mx = fmaxf(mx, v[u]);
  }
  for (int o = 32; o; o >>= 1) mx = fmaxf(mx, __shfl_xor(mx, o));
  if (lane == 0) red[wv] = mx;
  __syncthreads();
  float m2 = red[0];
  for (int i = 1; i < 16; ++i) m2 = fmaxf(m2, red[i]);
  float s = 0.f;
#pragma unroll
  for (int u = 0; u < 4; ++u) {
    v[u] = expf(v[u] - m2);
    s += v[u];
  }
  for (int o = 32; o; o >>= 1) s += __shfl_xor(s, o);
  if (lane == 0) red2[wv] = s;
  __syncthreads();
  float S = 0.f;
  for (int i = 0; i < 16; ++i) S += red2[i];
  float inv = 1.f / S;
#pragma unroll
  for (int u = 0; u < 4; ++u) w[t + u * 1024] = v[u] * inv;
}

// ---------------------------------------------------------------- k4b: partial weighted pooling (64 edges/block)
__global__ __launch_bounds__(256) void k4b_pool(const float* __restrict__ ef,
                                                const float* __restrict__ w,
                                                float* __restrict__ partial) {
  const int b = blockIdx.x, t = threadIdx.x;
  const int e0 = b * 64;
  for (int j = t; j < 304; j += 256) {
    float acc = 0.f;
    for (int e = 0; e < 64; ++e) acc += w[e0 + e] * ef[(size_t)(e0 + e) * 304 + j];
    partial[b * 304 + j] = acc;
  }
}

// ---------------------------------------------------------------- k4c: final reduce + two matvecs -> 3 logits
__global__ __launch_bounds__(256) void k4c_final(const float* __restrict__ partial,
                                                 const float* __restrict__ ecWp,
                                                 const float* __restrict__ ecb,
                                                 const float* __restrict__ fcW,
                                                 const float* __restrict__ fcb,
                                                 float* __restrict__ out) {
  __shared__ float pooled[304];
  __shared__ float o[304];
  const int t = threadIdx.x;
  for (int j = t; j < 304; j += 256) {
    float acc = 0.f;
    for (int b = 0; b < 64; ++b) acc += partial[b * 304 + j];
    pooled[j] = acc;
  }
  __syncthreads();
  for (int j2 = t; j2 < ND; j2 += 256) {
    float acc = ecb[j2];
    for (int j = 0; j < ND; ++j) acc += pooled[j] * ecWp[j * ND + j2];
    o[j2] = acc;
  }
  __syncthreads();
  if (t < 3) {
    float acc = fcb[t];
    for (int j2 = 0; j2 < ND; ++j2) acc += o[j2] * fcW[j2 * 3 + t];
    out[t] = acc;
  }
}

// ----------------------------------------------------------------
extern "C" void kernel_launch(void* const* d_in, const int* in_sizes, int n_in,
                              void* d_out, int out_size, void* d_ws, size_t ws_size,
                              hipStream_t stream) {
  const float* X = (const float*)d_in[0];
  const float* EF = (const float*)d_in[1];
  const float* INC = (const float*)d_in[2];
  const float* WATT = (const float*)d_in[3];
  const float* WPROJ = (const float*)d_in[4];
  const float* ALPHA = (const float*)d_in[5];
  const float* ECATT = (const float*)d_in[6];
  const float* ECWP = (const float*)d_in[7];
  const float* ECB = (const float*)d_in[8];
  const float* FCW = (const float*)d_in[9];
  const float* FCB = (const float*)d_in[10];

  char* ws = (char*)d_ws;
  f16* YT = (f16*)(ws);                      // 640*16384*2  = 20971520
  f16* X16 = (f16*)(ws + 20971520);          // 16384*320*2  = 10485760
  f16* WT = (f16*)(ws + 31457280);           // 320*320*2    =   204800
  float* Z = (float*)(ws + 31662080);        // 4096*640*4   = 10485760
  float* ef = (float*)(ws + 42147840);       // 4096*304*4   =  4980736
  float* sc = (float*)(ws + 47128576);       // 4096*4
  float* wv = (float*)(ws + 47144960);       // 4096*4
  float* pp = (float*)(ws + 47161344);       // 64*304*4

  hipLaunchKernelGGL(k0_wt, dim3(400), dim3(256), 0, stream, WATT, WT);
  hipLaunchKernelGGL(k1a_xprep, dim3(256), dim3(256), 0, stream, X, X16, YT);
  hipLaunchKernelGGL(k1b_xat, dim3(256), dim3(512), 0, stream, WT, X16, YT);
  hipLaunchKernelGGL(k2_bigmm, dim3(256), dim3(512), 0, stream, INC, YT, Z);
  hipLaunchKernelGGL(k3_edge, dim3(256), dim3(256), 0, stream, Z, EF, WPROJ, ALPHA,
                     ECATT, ef, sc);
  hipLaunchKernelGGL(k4a_softmax, dim3(1), dim3(1024), 0, stream, sc, wv);
  hipLaunchKernelGGL(k4b_pool, dim3(64), dim3(256), 0, stream, ef, wv, pp);
  hipLaunchKernelGGL(k4c_final, dim3(1), dim3(256), 0, stream, pp, ECWP, ECB, FCW,
                     FCB, (float*)d_out);
}